// Round 1
// baseline (269.638 us; speedup 1.0000x reference)
//
#include <hip/hip_runtime.h>
#include <hip/hip_bf16.h>
#include <cstdint>

#define H 1024
#define BSZ 4
#define LSEQ 2048
#define M_TOT (BSZ*LSEQ)   // 8192
#define NCH 32             // L-chunks for reduction/scan
#define LCH (LSEQ/NCH)     // 64

typedef __attribute__((ext_vector_type(4))) float  f32x4;
typedef __attribute__((ext_vector_type(8))) __bf16 bf16x8;
typedef __attribute__((ext_vector_type(4))) __bf16 bf16x4;

typedef __attribute__((address_space(1))) unsigned int as1_u32;
typedef __attribute__((address_space(3))) unsigned int as3_u32;

// async global->LDS, 16B per lane. lds ptr must be wave-uniform base;
// lane i's 16B land at base + i*16 (guide §5 caveat, m104/m108).
__device__ __forceinline__ void gld_lds16(const void* g, const void* l) {
    as1_u32* gp = reinterpret_cast<as1_u32*>((uintptr_t)g);
    as3_u32* lp = reinterpret_cast<as3_u32*>((uint32_t)(uintptr_t)l);
    __builtin_amdgcn_global_load_lds(gp, lp, 16, 0, 0);
}

// ---------------- GEMM: C[M,N] = A[M,K] @ B[N,K]^T, bf16 in, bf16 out -------
// 128x128 block tile, 4 waves, each wave 64x64 = 4x4 mfma_f32_16x16x32_bf16.
// LDS tiles 128x32 bf16, stored as 16B granules with XOR swizzle:
//   granule(m, octet) = m*4 + (octet ^ ((m>>1)&3))   -> 2-way max bank aliasing
// mode 1: += bias[col], softplus, for the delta GEMM.
__global__ __launch_bounds__(256) void gemm_bt(
    const __bf16* __restrict__ A,   // [M][K]
    const __bf16* __restrict__ B,   // [N][K]
    __bf16* __restrict__ O0, __bf16* __restrict__ O1, __bf16* __restrict__ O2,
    const float* __restrict__ bias,
    int K, int mode)
{
    __shared__ __align__(16) __bf16 ldsA[128*32];
    __shared__ __align__(16) __bf16 ldsB[128*32];

    const int tid  = threadIdx.x;
    const int lane = tid & 63;
    const int wid  = tid >> 6;
    const int wr   = (wid >> 1) * 64;   // wave row offset in 128-tile
    const int wc   = (wid & 1) * 64;    // wave col offset
    const int l15  = lane & 15;
    const int quad = lane >> 4;

    const int row0 = blockIdx.y * 128;
    const int col0 = blockIdx.x * 128;

    // staging: chunk t covers rows t*16..t*16+15 of the tile; lane -> (row, octet)
    const int srow = lane >> 2;
    const int soct = (lane & 3) ^ ((lane >> 3) & 3);   // XOR swizzle at store
    const __bf16* ag0 = A + (size_t)(row0 + (wid    )*16 + srow) * K + soct*8;
    const __bf16* ag1 = A + (size_t)(row0 + (wid + 4)*16 + srow) * K + soct*8;
    const __bf16* bg0 = B + (size_t)(col0 + (wid    )*16 + srow) * K + soct*8;
    const __bf16* bg1 = B + (size_t)(col0 + (wid + 4)*16 + srow) * K + soct*8;
    __bf16* lA0 = ldsA + (wid    )*512;
    __bf16* lA1 = ldsA + (wid + 4)*512;
    __bf16* lB0 = ldsB + (wid    )*512;
    __bf16* lB1 = ldsB + (wid + 4)*512;

    // fragment read offsets (element units): granule = m*4 + (quad ^ ((m>>1)&3))
    const int sw = (l15 >> 1) & 3;
    int aoff[4], boff[4];
#pragma unroll
    for (int i = 0; i < 4; ++i) {
        aoff[i] = ((wr + i*16 + l15) * 4 + (quad ^ sw)) * 8;
        boff[i] = ((wc + i*16 + l15) * 4 + (quad ^ sw)) * 8;
    }

    f32x4 acc[4][4] = {};

    const int KT = K >> 5;
    for (int kt = 0; kt < KT; ++kt) {
        gld_lds16(ag0, lA0);
        gld_lds16(ag1, lA1);
        gld_lds16(bg0, lB0);
        gld_lds16(bg1, lB1);
        ag0 += 32; ag1 += 32; bg0 += 32; bg1 += 32;
        __syncthreads();   // drains vmcnt -> LDS tiles complete

        bf16x8 af[4], bf[4];
#pragma unroll
        for (int i = 0; i < 4; ++i) af[i] = *(const bf16x8*)(ldsA + aoff[i]);
#pragma unroll
        for (int j = 0; j < 4; ++j) bf[j] = *(const bf16x8*)(ldsB + boff[j]);
#pragma unroll
        for (int i = 0; i < 4; ++i)
#pragma unroll
            for (int j = 0; j < 4; ++j)
                acc[i][j] = __builtin_amdgcn_mfma_f32_16x16x32_bf16(
                    af[i], bf[j], acc[i][j], 0, 0, 0);
        __syncthreads();   // protect LDS before next stage
    }

    // epilogue. C/D layout: col=lane&15, row=quad*4+reg (verified m89/m91).
    const int seg  = col0 >> 10;   // which 1024-col segment (block never straddles)
    __bf16* outp = seg == 0 ? O0 : (seg == 1 ? O1 : O2);
    const int colb = (col0 & 1023) + wc + l15;
    const int rowb = row0 + wr + quad*4;
#pragma unroll
    for (int i = 0; i < 4; ++i) {
#pragma unroll
        for (int j = 0; j < 4; ++j) {
            const int col = colb + j*16;
#pragma unroll
            for (int r = 0; r < 4; ++r) {
                float f = acc[i][j][r];
                if (mode) {
                    f += bias[col];
                    f = f > 15.f ? f : log1pf(expf(f));   // softplus
                }
                outp[(size_t)(rowb + i*16 + r) * H + col] = (__bf16)f;
            }
        }
    }
}

// ------------- cast f32 -> bf16: x, packed W_proj (skip Bs rows), W_delta ----
__global__ void cast_kernel(const float* __restrict__ x,
                            const float* __restrict__ Wp,
                            const float* __restrict__ Wd,
                            __bf16* __restrict__ xb,
                            __bf16* __restrict__ Wpb,
                            __bf16* __restrict__ Wdb)
{
    const int NX = (M_TOT * H) / 4;    // 2097152 float4s
    const int NP = (3072 * H) / 4;     // 786432
    int i = blockIdx.x * 256 + threadIdx.x;
    const f32x4* src; __bf16* dst; int si, di;
    if (i < NX) {
        src = (const f32x4*)x;  si = i; dst = xb;  di = i;
    } else if (i < NX + NP) {
        int j = i - NX;
        int row = j >> 8, cf = j & 255;           // 256 float4 per row
        int srow = row < 1024 ? row : row + 1024; // pack: skip Bs rows 1024..2047
        src = (const f32x4*)Wp; si = srow*256 + cf; dst = Wpb; di = j;
    } else {
        int j = i - NX - NP;
        src = (const f32x4*)Wd; si = j; dst = Wdb; di = j;
    }
    f32x4 v = src[si];
    bf16x4 o = { (__bf16)v[0], (__bf16)v[1], (__bf16)v[2], (__bf16)v[3] };
    *(bf16x4*)(dst + (size_t)di*4) = o;
}

// ------------- per-(b,h) chunk partials: uC, Csum, sum(delta) ----------------
__global__ void reduce_kernel(const float* __restrict__ x,
                              const __bf16* __restrict__ Cs,
                              const __bf16* __restrict__ delta,
                              float* __restrict__ pU, float* __restrict__ pC,
                              float* __restrict__ pD)
{
    const int c = blockIdx.x, b = blockIdx.z;
    const int h = blockIdx.y * 256 + threadIdx.x;
    size_t base = ((size_t)(b*LSEQ + c*LCH)) * H + h;
    float aU = 0.f, aC = 0.f, aD = 0.f;
#pragma unroll 4
    for (int l = 0; l < LCH; ++l) {
        size_t idx = base + (size_t)l * H;
        float cv = (float)Cs[idx];
        aU += x[idx] * cv;
        aC += cv;
        aD += (float)delta[idx];
    }
    int p = (b*NCH + c) * H + h;
    pU[p] = aU; pC[p] = aC; pD[p] = aD;
}

// ------------- finish reductions + exclusive scan of chunk sums --------------
__global__ void scan_kernel(const float* __restrict__ pU, const float* __restrict__ pC,
                            float* __restrict__ pD,
                            float* __restrict__ uC, float* __restrict__ Csum)
{
    int idx = blockIdx.x * 256 + threadIdx.x;   // 0..4095 = b*1024+h
    int b = idx >> 10, h = idx & 1023;
    float sU = 0.f, sC = 0.f, run = 0.f;
    for (int c = 0; c < NCH; ++c) {
        int p = (b*NCH + c) * H + h;
        sU += pU[p]; sC += pC[p];
        float t = pD[p]; pD[p] = run; run += t;   // exclusive scan in place
    }
    uC[idx] = sU; Csum[idx] = sC;
}

// ------------- final: y = exp(d*A1)*B1*uC + B1*cumsum(d)*Csum + res*D --------
__global__ void final_kernel(const __bf16* __restrict__ delta,
                             const __bf16* __restrict__ res,
                             const float* __restrict__ pD,
                             const float* __restrict__ uC,
                             const float* __restrict__ Csum,
                             const float* __restrict__ Av,
                             const float* __restrict__ Bv,
                             const float* __restrict__ Dv,
                             float* __restrict__ out)
{
    const int c = blockIdx.x, b = blockIdx.z;
    const int h = blockIdx.y * 256 + threadIdx.x;
    float run = pD[(b*NCH + c) * H + h];
    const float uc = uC[b*H + h], cs = Csum[b*H + h];
    const float a1 = Av[h], b1 = Bv[h], dd = Dv[0];
    size_t base = ((size_t)(b*LSEQ + c*LCH)) * H + h;
    for (int l = 0; l < LCH; ++l) {
        size_t idx = base + (size_t)l * H;
        float dv = (float)delta[idx];
        run += dv;                       // inclusive cumsum
        out[idx] = expf(dv*a1) * b1 * uc + run * b1 * cs + (float)res[idx] * dd;
    }
}

extern "C" void kernel_launch(void* const* d_in, const int* in_sizes, int n_in,
                              void* d_out, int out_size, void* d_ws, size_t ws_size,
                              hipStream_t stream)
{
    (void)in_sizes; (void)n_in; (void)out_size; (void)ws_size;
    const float* x  = (const float*)d_in[0];
    const float* Wp = (const float*)d_in[1];
    const float* Av = (const float*)d_in[2];   // (1,1,H)
    const float* Bv = (const float*)d_in[3];   // (1,H,1)
    const float* Dv = (const float*)d_in[4];   // (1,)
    const float* Wd = (const float*)d_in[5];
    const float* bd = (const float*)d_in[6];
    float* out = (float*)d_out;

    char* ws = (char*)d_ws;
    size_t o = 0;
    auto alloc = [&](size_t bytes) {
        void* p = ws + o; o += (bytes + 255) & ~(size_t)255; return p;
    };
    __bf16* xb   = (__bf16*)alloc((size_t)M_TOT * H * 2);   // 16 MB
    __bf16* Wpb  = (__bf16*)alloc((size_t)3072 * H * 2);    // 6 MB packed W_proj
    __bf16* Wdb  = (__bf16*)alloc((size_t)H * H * 2);       // 2 MB
    __bf16* d1   = (__bf16*)alloc((size_t)M_TOT * H * 2);   // delta pre-act
    __bf16* csb  = (__bf16*)alloc((size_t)M_TOT * H * 2);   // Cs
    __bf16* resb = (__bf16*)alloc((size_t)M_TOT * H * 2);   // residual
    __bf16* db   = (__bf16*)alloc((size_t)M_TOT * H * 2);   // softplus(delta)
    float*  pU   = (float*)alloc((size_t)BSZ * NCH * H * 4);
    float*  pC   = (float*)alloc((size_t)BSZ * NCH * H * 4);
    float*  pD   = (float*)alloc((size_t)BSZ * NCH * H * 4);
    float*  uC   = (float*)alloc((size_t)BSZ * H * 4);
    float*  cS   = (float*)alloc((size_t)BSZ * H * 4);

    cast_kernel<<<12288, 256, 0, stream>>>(x, Wp, Wd, xb, Wpb, Wdb);
    // GEMM1: [8192,1024] @ [3072,1024]^T -> delta_pre | Cs | residual
    gemm_bt<<<dim3(24, 64), 256, 0, stream>>>(xb, Wpb, d1, csb, resb, nullptr, H, 0);
    // GEMM2: [8192,1024] @ [1024,1024]^T + b_delta, softplus
    gemm_bt<<<dim3(8, 64), 256, 0, stream>>>(d1, Wdb, db, db, db, bd, H, 1);
    reduce_kernel<<<dim3(NCH, 4, BSZ), 256, 0, stream>>>(x, csb, db, pU, pC, pD);
    scan_kernel<<<16, 256, 0, stream>>>(pU, pC, pD, uC, cS);
    final_kernel<<<dim3(NCH, 4, BSZ), 256, 0, stream>>>(db, resb, pD, uC, cS,
                                                        Av, Bv, Dv, out);
}

// Round 2
// 242.006 us; speedup vs baseline: 1.1142x; 1.1142x over previous
//
#include <hip/hip_runtime.h>
#include <hip/hip_bf16.h>
#include <cstdint>

#define H 1024
#define BSZ 4
#define LSEQ 2048
#define M_TOT (BSZ*LSEQ)   // 8192
#define NCH 32             // L-chunks for reduction/scan
#define LCH (LSEQ/NCH)     // 64

typedef __attribute__((ext_vector_type(4))) float  f32x4;
typedef __attribute__((ext_vector_type(8))) __bf16 bf16x8;
typedef __attribute__((ext_vector_type(4))) __bf16 bf16x4;

typedef __attribute__((address_space(1))) unsigned int as1_u32;
typedef __attribute__((address_space(3))) unsigned int as3_u32;

// async global->LDS, 16B per lane. lds ptr must be wave-uniform base;
// lane i's 16B land at base + i*16 (guide §5 caveat, m104/m108).
__device__ __forceinline__ void gld_lds16(const void* g, const void* l) {
    as1_u32* gp = reinterpret_cast<as1_u32*>((uintptr_t)g);
    as3_u32* lp = reinterpret_cast<as3_u32*>((uint32_t)(uintptr_t)l);
    __builtin_amdgcn_global_load_lds(gp, lp, 16, 0, 0);
}

// ---------------- GEMM: C[M,N] = A[M,K] @ B[N,K]^T, bf16 in, bf16 out -------
// 128x128 block tile, 4 waves, each wave 64x64 = 4x4 mfma_f32_16x16x32_bf16.
// Double-buffered LDS (2 x 16KB), ONE barrier per K-tile:
//   iter kt: __syncthreads (drains loads for tile kt, issued last iter);
//            issue loads tile kt+1 -> buf[nxt]; compute from buf[cur].
// LDS tiles 128x32 bf16 as 16B granules with XOR swizzle:
//   granule(m, octet) = m*4 + (octet ^ ((m>>1)&3)) -> 2-way max bank aliasing.
// MODE 1: += bias[col], softplus (delta GEMM).
template<int KT, int MODE>
__global__ __launch_bounds__(256, 3) void gemm_bt(
    const __bf16* __restrict__ A,   // [M][KT*32]
    const __bf16* __restrict__ B,   // [N][KT*32]
    __bf16* __restrict__ O0, __bf16* __restrict__ O1, __bf16* __restrict__ O2,
    const float* __restrict__ bias)
{
    constexpr int K = KT * 32;
    __shared__ __align__(16) __bf16 lds[2 * 8192];   // [buf][A:4096 | B:4096]

    const int tid  = threadIdx.x;
    const int lane = tid & 63;
    const int wid  = tid >> 6;
    const int wr   = (wid >> 1) * 64;
    const int wc   = (wid & 1) * 64;
    const int l15  = lane & 15;
    const int quad = lane >> 4;

    const int row0 = blockIdx.y * 128;
    const int col0 = blockIdx.x * 128;

    // staging: wave wid covers 16-row chunks {wid, wid+4}; lane -> (row, octet)
    const int srow = lane >> 2;
    const int soct = (lane & 3) ^ ((lane >> 3) & 3);   // XOR swizzle at store
    const __bf16* ag0 = A + (size_t)(row0 + (wid    )*16 + srow) * K + soct*8;
    const __bf16* ag1 = A + (size_t)(row0 + (wid + 4)*16 + srow) * K + soct*8;
    const __bf16* bg0 = B + (size_t)(col0 + (wid    )*16 + srow) * K + soct*8;
    const __bf16* bg1 = B + (size_t)(col0 + (wid + 4)*16 + srow) * K + soct*8;
    const int lA0 = (wid    )*512;
    const int lA1 = (wid + 4)*512;
    const int lB0 = 4096 + (wid    )*512;
    const int lB1 = 4096 + (wid + 4)*512;

    // fragment read offsets (elements): granule = m*4 + (quad ^ ((m>>1)&3))
    const int sw = (l15 >> 1) & 3;
    int aoff[4], boff[4];
#pragma unroll
    for (int i = 0; i < 4; ++i) {
        aoff[i] =        ((wr + i*16 + l15) * 4 + (quad ^ sw)) * 8;
        boff[i] = 4096 + ((wc + i*16 + l15) * 4 + (quad ^ sw)) * 8;
    }

    f32x4 acc[4][4] = {};

    auto stage = [&](int buf) {
        __bf16* base = lds + buf * 8192;
        gld_lds16(ag0, base + lA0);
        gld_lds16(ag1, base + lA1);
        gld_lds16(bg0, base + lB0);
        gld_lds16(bg1, base + lB1);
        ag0 += 32; ag1 += 32; bg0 += 32; bg1 += 32;
    };
    auto compute = [&](int buf) {
        const __bf16* base = lds + buf * 8192;
        bf16x8 af[4], bf[4];
#pragma unroll
        for (int i = 0; i < 4; ++i) af[i] = *(const bf16x8*)(base + aoff[i]);
#pragma unroll
        for (int j = 0; j < 4; ++j) bf[j] = *(const bf16x8*)(base + boff[j]);
#pragma unroll
        for (int i = 0; i < 4; ++i)
#pragma unroll
            for (int j = 0; j < 4; ++j)
                acc[i][j] = __builtin_amdgcn_mfma_f32_16x16x32_bf16(
                    af[i], bf[j], acc[i][j], 0, 0, 0);
    };

    stage(0);                                  // prefetch tile 0
#pragma unroll 2
    for (int kt = 0; kt < KT; ++kt) {
        __syncthreads();                       // tile kt landed; buf[nxt] free
        if (kt + 1 < KT) stage((kt + 1) & 1);  // prefetch tile kt+1
        compute(kt & 1);                       // MFMA on tile kt
    }

    // epilogue. C/D layout: col=lane&15, row=quad*4+reg (verified m89/m91).
    const int seg  = col0 >> 10;   // 1024-col segment (blocks never straddle)
    __bf16* outp = seg == 0 ? O0 : (seg == 1 ? O1 : O2);
    const int colb = (col0 & 1023) + wc + l15;
    const int rowb = row0 + wr + quad*4;
#pragma unroll
    for (int i = 0; i < 4; ++i) {
#pragma unroll
        for (int j = 0; j < 4; ++j) {
            const int col = colb + j*16;
#pragma unroll
            for (int r = 0; r < 4; ++r) {
                float f = acc[i][j][r];
                if (MODE) {
                    f += bias[col];
                    f = f > 15.f ? f : log1pf(expf(f));   // softplus
                }
                outp[(size_t)(rowb + i*16 + r) * H + col] = (__bf16)f;
            }
        }
    }
}

// ------------- cast f32 -> bf16: x, packed W_proj (skip Bs rows), W_delta ----
__global__ void cast_kernel(const float* __restrict__ x,
                            const float* __restrict__ Wp,
                            const float* __restrict__ Wd,
                            __bf16* __restrict__ xb,
                            __bf16* __restrict__ Wpb,
                            __bf16* __restrict__ Wdb)
{
    const int NX = (M_TOT * H) / 4;    // 2097152 float4s
    const int NP = (3072 * H) / 4;     // 786432
    int i = blockIdx.x * 256 + threadIdx.x;
    const f32x4* src; __bf16* dst; int si, di;
    if (i < NX) {
        src = (const f32x4*)x;  si = i; dst = xb;  di = i;
    } else if (i < NX + NP) {
        int j = i - NX;
        int row = j >> 8, cf = j & 255;           // 256 float4 per row
        int srow = row < 1024 ? row : row + 1024; // pack: skip Bs rows 1024..2047
        src = (const f32x4*)Wp; si = srow*256 + cf; dst = Wpb; di = j;
    } else {
        int j = i - NX - NP;
        src = (const f32x4*)Wd; si = j; dst = Wdb; di = j;
    }
    f32x4 v = src[si];
    bf16x4 o = { (__bf16)v[0], (__bf16)v[1], (__bf16)v[2], (__bf16)v[3] };
    *(bf16x4*)(dst + (size_t)di*4) = o;
}

// ------------- per-(b,h) chunk partials: uC, Csum, sum(delta) ----------------
__global__ void reduce_kernel(const __bf16* __restrict__ xb,
                              const __bf16* __restrict__ Cs,
                              const __bf16* __restrict__ delta,
                              float* __restrict__ pU, float* __restrict__ pC,
                              float* __restrict__ pD)
{
    const int c = blockIdx.x, b = blockIdx.z;
    const int h = blockIdx.y * 256 + threadIdx.x;
    size_t base = ((size_t)(b*LSEQ + c*LCH)) * H + h;
    float aU = 0.f, aC = 0.f, aD = 0.f;
#pragma unroll 4
    for (int l = 0; l < LCH; ++l) {
        size_t idx = base + (size_t)l * H;
        float cv = (float)Cs[idx];
        aU += (float)xb[idx] * cv;
        aC += cv;
        aD += (float)delta[idx];
    }
    int p = (b*NCH + c) * H + h;
    pU[p] = aU; pC[p] = aC; pD[p] = aD;
}

// ------------- finish reductions + exclusive scan of chunk sums --------------
__global__ void scan_kernel(const float* __restrict__ pU, const float* __restrict__ pC,
                            float* __restrict__ pD,
                            float* __restrict__ uC, float* __restrict__ Csum)
{
    int idx = blockIdx.x * 256 + threadIdx.x;   // 0..4095 = b*1024+h
    int b = idx >> 10, h = idx & 1023;
    float sU = 0.f, sC = 0.f, run = 0.f;
    for (int c = 0; c < NCH; ++c) {
        int p = (b*NCH + c) * H + h;
        sU += pU[p]; sC += pC[p];
        float t = pD[p]; pD[p] = run; run += t;   // exclusive scan in place
    }
    uC[idx] = sU; Csum[idx] = sC;
}

// ------------- final: y = exp(d*A1)*B1*uC + B1*cumsum(d)*Csum + res*D --------
__global__ void final_kernel(const __bf16* __restrict__ delta,
                             const __bf16* __restrict__ res,
                             const float* __restrict__ pD,
                             const float* __restrict__ uC,
                             const float* __restrict__ Csum,
                             const float* __restrict__ Av,
                             const float* __restrict__ Bv,
                             const float* __restrict__ Dv,
                             float* __restrict__ out)
{
    const int c = blockIdx.x, b = blockIdx.z;
    const int h = blockIdx.y * 256 + threadIdx.x;
    float run = pD[(b*NCH + c) * H + h];
    const float uc = uC[b*H + h], cs = Csum[b*H + h];
    const float a1 = Av[h], b1 = Bv[h], dd = Dv[0];
    size_t base = ((size_t)(b*LSEQ + c*LCH)) * H + h;
    for (int l = 0; l < LCH; ++l) {
        size_t idx = base + (size_t)l * H;
        float dv = (float)delta[idx];
        run += dv;                       // inclusive cumsum
        out[idx] = expf(dv*a1) * b1 * uc + run * b1 * cs + (float)res[idx] * dd;
    }
}

extern "C" void kernel_launch(void* const* d_in, const int* in_sizes, int n_in,
                              void* d_out, int out_size, void* d_ws, size_t ws_size,
                              hipStream_t stream)
{
    (void)in_sizes; (void)n_in; (void)out_size; (void)ws_size;
    const float* x  = (const float*)d_in[0];
    const float* Wp = (const float*)d_in[1];
    const float* Av = (const float*)d_in[2];   // (1,1,H)
    const float* Bv = (const float*)d_in[3];   // (1,H,1)
    const float* Dv = (const float*)d_in[4];   // (1,)
    const float* Wd = (const float*)d_in[5];
    const float* bd = (const float*)d_in[6];
    float* out = (float*)d_out;

    char* ws = (char*)d_ws;
    size_t o = 0;
    auto alloc = [&](size_t bytes) {
        void* p = ws + o; o += (bytes + 255) & ~(size_t)255; return p;
    };
    __bf16* xb   = (__bf16*)alloc((size_t)M_TOT * H * 2);   // 16 MB
    __bf16* Wpb  = (__bf16*)alloc((size_t)3072 * H * 2);    // 6 MB packed W_proj
    __bf16* Wdb  = (__bf16*)alloc((size_t)H * H * 2);       // 2 MB
    __bf16* d1   = (__bf16*)alloc((size_t)M_TOT * H * 2);   // delta pre-act
    __bf16* csb  = (__bf16*)alloc((size_t)M_TOT * H * 2);   // Cs
    __bf16* resb = (__bf16*)alloc((size_t)M_TOT * H * 2);   // residual
    __bf16* db   = (__bf16*)alloc((size_t)M_TOT * H * 2);   // softplus(delta)
    float*  pU   = (float*)alloc((size_t)BSZ * NCH * H * 4);
    float*  pC   = (float*)alloc((size_t)BSZ * NCH * H * 4);
    float*  pD   = (float*)alloc((size_t)BSZ * NCH * H * 4);
    float*  uC   = (float*)alloc((size_t)BSZ * H * 4);
    float*  cS   = (float*)alloc((size_t)BSZ * H * 4);

    cast_kernel<<<12288, 256, 0, stream>>>(x, Wp, Wd, xb, Wpb, Wdb);
    // GEMM1: [8192,1024] @ [3072,1024]^T -> delta_pre | Cs | residual
    gemm_bt<32, 0><<<dim3(24, 64), 256, 0, stream>>>(xb, Wpb, d1, csb, resb, nullptr);
    // GEMM2: [8192,1024] @ [1024,1024]^T + b_delta, softplus
    gemm_bt<32, 1><<<dim3(8, 64), 256, 0, stream>>>(d1, Wdb, db, db, db, bd);
    reduce_kernel<<<dim3(NCH, 4, BSZ), 256, 0, stream>>>(xb, csb, db, pU, pC, pD);
    scan_kernel<<<16, 256, 0, stream>>>(pU, pC, pD, uC, cS);
    final_kernel<<<dim3(NCH, 4, BSZ), 256, 0, stream>>>(db, resb, pD, uC, cS,
                                                        Av, Bv, Dv, out);
}

// Round 3
// 241.724 us; speedup vs baseline: 1.1155x; 1.0012x over previous
//
#include <hip/hip_runtime.h>
#include <hip/hip_bf16.h>
#include <cstdint>

#define H 1024
#define BSZ 4
#define LSEQ 2048
#define M_TOT (BSZ*LSEQ)   // 8192
#define NCH 32             // L-chunks for the delta scan
#define LCH (LSEQ/NCH)     // 64

typedef __attribute__((ext_vector_type(4))) float  f32x4;
typedef __attribute__((ext_vector_type(8))) __bf16 bf16x8;
typedef __attribute__((ext_vector_type(4))) __bf16 bf16x4;

typedef __attribute__((address_space(1))) unsigned int as1_u32;
typedef __attribute__((address_space(3))) unsigned int as3_u32;

__device__ __forceinline__ void gld_lds16(const void* g, const void* l) {
    as1_u32* gp = reinterpret_cast<as1_u32*>((uintptr_t)g);
    as3_u32* lp = reinterpret_cast<as3_u32*>((uint32_t)(uintptr_t)l);
    __builtin_amdgcn_global_load_lds(gp, lp, 16, 0, 0);
}

// ---------------- GEMM: C[M,N] = A[M,K] @ B[N,K]^T, bf16 in ----------------
// 128x128 tile, 4 waves x (4x4) mfma_f32_16x16x32_bf16, double-buffered LDS,
// one barrier per K-tile, XOR-swizzled 16B granules (2-way max bank alias).
// MODE 0 (proj GEMM, N=3072): seg0 -> store d1; seg2 -> store residual;
//   seg1 (Cs): DO NOT store — accumulate per-col sum(Cs), sum(x*Cs) via
//   quad-shuffle + atomicAdd (wave rows all lie in one batch b).
// MODE 1 (delta GEMM): +bias, softplus, store db, and accumulate per-col
//   per-64-row-chunk sum(delta) via quad-shuffle + atomicAdd (wave rows all
//   lie in one 64-chunk: rows = wr + quad*4 + i*16 + r ∈ wr+[0,64)).
template<int KT, int MODE>
__global__ __launch_bounds__(256, 3) void gemm_bt(
    const __bf16* __restrict__ A,
    const __bf16* __restrict__ B,
    __bf16* __restrict__ O0,          // MODE0: d1   MODE1: db
    __bf16* __restrict__ O2,          // MODE0: resb
    const __bf16* __restrict__ xb,    // MODE0: x (bf16) for uC
    const float* __restrict__ bias,   // MODE1
    float* __restrict__ r0,           // MODE0: pU[b*H+h]   MODE1: pD[chunk*H+h]
    float* __restrict__ r1)           // MODE0: pC[b*H+h]
{
    constexpr int K = KT * 32;
    __shared__ __align__(16) __bf16 lds[2 * 8192];   // [buf][A:4096 | B:4096]

    const int tid  = threadIdx.x;
    const int lane = tid & 63;
    const int wid  = tid >> 6;
    const int wr   = (wid >> 1) * 64;
    const int wc   = (wid & 1) * 64;
    const int l15  = lane & 15;
    const int quad = lane >> 4;

    const int row0 = blockIdx.y * 128;
    const int col0 = blockIdx.x * 128;

    const int srow = lane >> 2;
    const int soct = (lane & 3) ^ ((lane >> 3) & 3);   // XOR swizzle at store
    const __bf16* ag0 = A + (size_t)(row0 + (wid    )*16 + srow) * K + soct*8;
    const __bf16* ag1 = A + (size_t)(row0 + (wid + 4)*16 + srow) * K + soct*8;
    const __bf16* bg0 = B + (size_t)(col0 + (wid    )*16 + srow) * K + soct*8;
    const __bf16* bg1 = B + (size_t)(col0 + (wid + 4)*16 + srow) * K + soct*8;
    const int lA0 = (wid    )*512;
    const int lA1 = (wid + 4)*512;
    const int lB0 = 4096 + (wid    )*512;
    const int lB1 = 4096 + (wid + 4)*512;

    const int sw = (l15 >> 1) & 3;
    int aoff[4], boff[4];
#pragma unroll
    for (int i = 0; i < 4; ++i) {
        aoff[i] =        ((wr + i*16 + l15) * 4 + (quad ^ sw)) * 8;
        boff[i] = 4096 + ((wc + i*16 + l15) * 4 + (quad ^ sw)) * 8;
    }

    f32x4 acc[4][4] = {};

    auto stage = [&](int buf) {
        __bf16* base = lds + buf * 8192;
        gld_lds16(ag0, base + lA0);
        gld_lds16(ag1, base + lA1);
        gld_lds16(bg0, base + lB0);
        gld_lds16(bg1, base + lB1);
        ag0 += 32; ag1 += 32; bg0 += 32; bg1 += 32;
    };
    auto compute = [&](int buf) {
        const __bf16* base = lds + buf * 8192;
        bf16x8 af[4], bf[4];
#pragma unroll
        for (int i = 0; i < 4; ++i) af[i] = *(const bf16x8*)(base + aoff[i]);
#pragma unroll
        for (int j = 0; j < 4; ++j) bf[j] = *(const bf16x8*)(base + boff[j]);
#pragma unroll
        for (int i = 0; i < 4; ++i)
#pragma unroll
            for (int j = 0; j < 4; ++j)
                acc[i][j] = __builtin_amdgcn_mfma_f32_16x16x32_bf16(
                    af[i], bf[j], acc[i][j], 0, 0, 0);
    };

    stage(0);
#pragma unroll 2
    for (int kt = 0; kt < KT; ++kt) {
        __syncthreads();
        if (kt + 1 < KT) stage((kt + 1) & 1);
        compute(kt & 1);
    }

    // epilogue. C/D layout: col=lane&15, row=quad*4+reg (verified m89/m91).
    const int colb = (col0 & 1023) + wc + l15;
    const int rowb = row0 + wr + quad*4;

    if (MODE == 0) {
        const int seg = col0 >> 10;
        if (seg == 1) {
            // uC / Csum fused reduction; Cs never materialized.
            const int b = row0 >> 11;
#pragma unroll
            for (int j = 0; j < 4; ++j) {
                const int col = colb + j*16;
                float su = 0.f, sc = 0.f;
#pragma unroll
                for (int i = 0; i < 4; ++i)
#pragma unroll
                    for (int r = 0; r < 4; ++r) {
                        float cv = acc[i][j][r];
                        float xv = (float)xb[(size_t)(rowb + i*16 + r) * H + col];
                        su += xv * cv;
                        sc += cv;
                    }
                su += __shfl_down(su, 32); su += __shfl_down(su, 16);
                sc += __shfl_down(sc, 32); sc += __shfl_down(sc, 16);
                if (quad == 0) {
                    atomicAdd(r0 + b*H + col, su);
                    atomicAdd(r1 + b*H + col, sc);
                }
            }
        } else {
            __bf16* outp = seg == 0 ? O0 : O2;
#pragma unroll
            for (int i = 0; i < 4; ++i)
#pragma unroll
                for (int j = 0; j < 4; ++j) {
                    const int col = colb + j*16;
#pragma unroll
                    for (int r = 0; r < 4; ++r)
                        outp[(size_t)(rowb + i*16 + r) * H + col] =
                            (__bf16)acc[i][j][r];
                }
        }
    } else {
        // delta GEMM: bias + softplus + store + fused per-chunk sum.
        const int chunk = (row0 + wr) >> 6;   // == b*NCH + c  (LCH==64)
#pragma unroll
        for (int j = 0; j < 4; ++j) {
            const int col = colb + j*16;
            const float bv = bias[col];
            float s = 0.f;
#pragma unroll
            for (int i = 0; i < 4; ++i)
#pragma unroll
                for (int r = 0; r < 4; ++r) {
                    float f = acc[i][j][r] + bv;
                    f = f > 15.f ? f : log1pf(expf(f));   // softplus
                    O0[(size_t)(rowb + i*16 + r) * H + col] = (__bf16)f;
                    s += f;
                }
            s += __shfl_down(s, 32); s += __shfl_down(s, 16);
            if (quad == 0) atomicAdd(r0 + chunk*H + col, s);
        }
    }
}

// ------------- cast f32 -> bf16: x, packed W_proj (skip Bs rows), W_delta ----
__global__ void cast_kernel(const float* __restrict__ x,
                            const float* __restrict__ Wp,
                            const float* __restrict__ Wd,
                            __bf16* __restrict__ xb,
                            __bf16* __restrict__ Wpb,
                            __bf16* __restrict__ Wdb)
{
    const int NX = (M_TOT * H) / 4;    // 2097152 float4s
    const int NP = (3072 * H) / 4;     // 786432
    int i = blockIdx.x * 256 + threadIdx.x;
    const f32x4* src; __bf16* dst; int si, di;
    if (i < NX) {
        src = (const f32x4*)x;  si = i; dst = xb;  di = i;
    } else if (i < NX + NP) {
        int j = i - NX;
        int row = j >> 8, cf = j & 255;           // 256 float4 per row
        int srow = row < 1024 ? row : row + 1024; // pack: skip Bs rows 1024..2047
        src = (const f32x4*)Wp; si = srow*256 + cf; dst = Wpb; di = j;
    } else {
        int j = i - NX - NP;
        src = (const f32x4*)Wd; si = j; dst = Wdb; di = j;
    }
    f32x4 v = src[si];
    bf16x4 o = { (__bf16)v[0], (__bf16)v[1], (__bf16)v[2], (__bf16)v[3] };
    *(bf16x4*)(dst + (size_t)di*4) = o;
}

// ------------- exclusive scan of per-chunk delta sums (in place) -------------
__global__ void scan_kernel(float* __restrict__ pD)
{
    int idx = blockIdx.x * 256 + threadIdx.x;   // 0..4095 = b*1024+h
    int b = idx >> 10, h = idx & 1023;
    float run = 0.f;
    for (int c = 0; c < NCH; ++c) {
        int p = (b*NCH + c) * H + h;
        float t = pD[p]; pD[p] = run; run += t;
    }
}

// ------------- final: y = exp(d*A1)*B1*uC + B1*cumsum(d)*Csum + res*D --------
__global__ void final_kernel(const __bf16* __restrict__ delta,
                             const __bf16* __restrict__ res,
                             const float* __restrict__ pD,
                             const float* __restrict__ uC,
                             const float* __restrict__ Csum,
                             const float* __restrict__ Av,
                             const float* __restrict__ Bv,
                             const float* __restrict__ Dv,
                             float* __restrict__ out)
{
    const int c = blockIdx.x, b = blockIdx.z;
    const int h = blockIdx.y * 256 + threadIdx.x;
    float run = pD[(b*NCH + c) * H + h];
    const float uc = uC[b*H + h], cs = Csum[b*H + h];
    const float a1 = Av[h], b1 = Bv[h], dd = Dv[0];
    size_t base = ((size_t)(b*LSEQ + c*LCH)) * H + h;
    for (int l = 0; l < LCH; ++l) {
        size_t idx = base + (size_t)l * H;
        float dv = (float)delta[idx];
        run += dv;                       // inclusive cumsum
        out[idx] = expf(dv*a1) * b1 * uc + run * b1 * cs + (float)res[idx] * dd;
    }
}

extern "C" void kernel_launch(void* const* d_in, const int* in_sizes, int n_in,
                              void* d_out, int out_size, void* d_ws, size_t ws_size,
                              hipStream_t stream)
{
    (void)in_sizes; (void)n_in; (void)out_size; (void)ws_size;
    const float* x  = (const float*)d_in[0];
    const float* Wp = (const float*)d_in[1];
    const float* Av = (const float*)d_in[2];   // (1,1,H)
    const float* Bv = (const float*)d_in[3];   // (1,H,1)
    const float* Dv = (const float*)d_in[4];   // (1,)
    const float* Wd = (const float*)d_in[5];
    const float* bd = (const float*)d_in[6];
    float* out = (float*)d_out;

    char* ws = (char*)d_ws;
    size_t o = 0;
    auto alloc = [&](size_t bytes) {
        void* p = ws + o; o += (bytes + 255) & ~(size_t)255; return p;
    };
    __bf16* xb   = (__bf16*)alloc((size_t)M_TOT * H * 2);   // 16 MB
    __bf16* Wpb  = (__bf16*)alloc((size_t)3072 * H * 2);    // 6 MB packed W_proj
    __bf16* Wdb  = (__bf16*)alloc((size_t)H * H * 2);       // 2 MB
    __bf16* d1   = (__bf16*)alloc((size_t)M_TOT * H * 2);   // delta pre-act
    __bf16* resb = (__bf16*)alloc((size_t)M_TOT * H * 2);   // residual
    __bf16* db   = (__bf16*)alloc((size_t)M_TOT * H * 2);   // softplus(delta)
    // contiguous fp32 accumulators (one memset): pU | pC | pD
    float*  pU   = (float*)alloc((size_t)BSZ * H * 4);
    float*  pC   = (float*)alloc((size_t)BSZ * H * 4);
    float*  pD   = (float*)alloc((size_t)BSZ * NCH * H * 4);

    size_t accBytes = (size_t)(BSZ*H + BSZ*H + BSZ*NCH*H) * 4 + 512;
    hipMemsetAsync(pU, 0, accBytes, stream);   // zero all three accumulators

    cast_kernel<<<12288, 256, 0, stream>>>(x, Wp, Wd, xb, Wpb, Wdb);
    // GEMM1: [8192,1024] @ [3072,1024]^T -> d1 | (uC,Csum atomics) | resb
    gemm_bt<32, 0><<<dim3(24, 64), 256, 0, stream>>>(
        xb, Wpb, d1, resb, xb, nullptr, pU, pC);
    // GEMM2: [8192,1024] @ [1024,1024]^T + bias, softplus -> db + pD atomics
    gemm_bt<32, 1><<<dim3(8, 64), 256, 0, stream>>>(
        d1, Wdb, db, nullptr, nullptr, bd, pD, nullptr);
    scan_kernel<<<16, 256, 0, stream>>>(pD);
    final_kernel<<<dim3(NCH, 4, BSZ), 256, 0, stream>>>(db, resb, pD, pU, pC,
                                                        Av, Bv, Dv, out);
}

// Round 4
// 238.518 us; speedup vs baseline: 1.1305x; 1.0134x over previous
//
#include <hip/hip_runtime.h>
#include <hip/hip_bf16.h>
#include <cstdint>

#define H 1024
#define BSZ 4
#define LSEQ 2048
#define M_TOT (BSZ*LSEQ)   // 8192
#define NCH 32             // L-chunks for the delta scan
#define LCH (LSEQ/NCH)     // 64

typedef __attribute__((ext_vector_type(4))) float  f32x4;
typedef __attribute__((ext_vector_type(2))) float  f32x2;
typedef __attribute__((ext_vector_type(8))) __bf16 bf16x8;
typedef __attribute__((ext_vector_type(4))) __bf16 bf16x4;
typedef __attribute__((ext_vector_type(2))) __bf16 bf16x2;

typedef __attribute__((address_space(1))) unsigned int as1_u32;
typedef __attribute__((address_space(3))) unsigned int as3_u32;

__device__ __forceinline__ void gld_lds16(const void* g, const void* l) {
    as1_u32* gp = reinterpret_cast<as1_u32*>((uintptr_t)g);
    as3_u32* lp = reinterpret_cast<as3_u32*>((uint32_t)(uintptr_t)l);
    __builtin_amdgcn_global_load_lds(gp, lp, 16, 0, 0);
}

// ---------------- GEMM: C[M,N] = A[M,K] @ B[N,K]^T, bf16 in ----------------
// 128x128 tile, 4 waves x (4x4) mfma_f32_16x16x32_bf16, double-buffered LDS,
// one barrier per K-tile, XOR-swizzled 16B granules.
// MODE 0: plain store to O0 (used for Wfuse = Wd @ Wp1, all cols < 1024).
// MODE 2 (the one big GEMM, N=3072):
//   seg0 (delta = x@Wfuse^T): +bias, softplus, store db, per-64-row-chunk
//     col-sum -> pD plain store (exactly one writer per (chunk,col)).
//   seg1 (Cs): never stored. C tile -> LDS bf16 [128][132], column-parallel
//     reduce with coalesced xb reloads -> atomicAdd pU (sum x*Cs), pC (sum Cs).
//   seg2 (residual): store O2.
template<int KT, int MODE>
__global__ __launch_bounds__(256, 3) void gemm_bt(
    const __bf16* __restrict__ A,
    const __bf16* __restrict__ B,
    __bf16* __restrict__ O0,
    __bf16* __restrict__ O2,
    const __bf16* __restrict__ xb,
    const float* __restrict__ bias,
    float* __restrict__ pD,
    float* __restrict__ pU,
    float* __restrict__ pC)
{
    constexpr int K = KT * 32;
    // K-loop: [0,16384) = 2 x (A:4096 | B:4096). seg1 epilogue reuses
    // [0,16896) as 128x132 bf16 Cs tile + 256 floats of partials at 16896.
    __shared__ __align__(16) __bf16 lds[17408];

    const int tid  = threadIdx.x;
    const int lane = tid & 63;
    const int wid  = tid >> 6;
    const int wr   = (wid >> 1) * 64;
    const int wc   = (wid & 1) * 64;
    const int l15  = lane & 15;
    const int quad = lane >> 4;

    const int row0 = blockIdx.y * 128;
    const int col0 = blockIdx.x * 128;

    const int srow = lane >> 2;
    const int soct = (lane & 3) ^ ((lane >> 3) & 3);   // XOR swizzle at store
    const __bf16* ag0 = A + (size_t)(row0 + (wid    )*16 + srow) * K + soct*8;
    const __bf16* ag1 = A + (size_t)(row0 + (wid + 4)*16 + srow) * K + soct*8;
    const __bf16* bg0 = B + (size_t)(col0 + (wid    )*16 + srow) * K + soct*8;
    const __bf16* bg1 = B + (size_t)(col0 + (wid + 4)*16 + srow) * K + soct*8;
    const int lA0 = (wid    )*512;
    const int lA1 = (wid + 4)*512;
    const int lB0 = 4096 + (wid    )*512;
    const int lB1 = 4096 + (wid + 4)*512;

    const int sw = (l15 >> 1) & 3;
    int aoff[4], boff[4];
#pragma unroll
    for (int i = 0; i < 4; ++i) {
        aoff[i] =        ((wr + i*16 + l15) * 4 + (quad ^ sw)) * 8;
        boff[i] = 4096 + ((wc + i*16 + l15) * 4 + (quad ^ sw)) * 8;
    }

    f32x4 acc[4][4] = {};

    auto stage = [&](int buf) {
        __bf16* base = lds + buf * 8192;
        gld_lds16(ag0, base + lA0);
        gld_lds16(ag1, base + lA1);
        gld_lds16(bg0, base + lB0);
        gld_lds16(bg1, base + lB1);
        ag0 += 32; ag1 += 32; bg0 += 32; bg1 += 32;
    };
    auto compute = [&](int buf) {
        const __bf16* base = lds + buf * 8192;
        bf16x8 af[4], bf[4];
#pragma unroll
        for (int i = 0; i < 4; ++i) af[i] = *(const bf16x8*)(base + aoff[i]);
#pragma unroll
        for (int j = 0; j < 4; ++j) bf[j] = *(const bf16x8*)(base + boff[j]);
#pragma unroll
        for (int i = 0; i < 4; ++i)
#pragma unroll
            for (int j = 0; j < 4; ++j)
                acc[i][j] = __builtin_amdgcn_mfma_f32_16x16x32_bf16(
                    af[i], bf[j], acc[i][j], 0, 0, 0);
    };

    stage(0);
#pragma unroll 2
    for (int kt = 0; kt < KT; ++kt) {
        __syncthreads();
        if (kt + 1 < KT) stage((kt + 1) & 1);
        compute(kt & 1);
    }

    // epilogue. C/D layout: col=lane&15, row=quad*4+reg (verified m89/m91).
    const int colb = (col0 & 1023) + wc + l15;
    const int rowb = row0 + wr + quad*4;

    if (MODE == 0) {
#pragma unroll
        for (int i = 0; i < 4; ++i)
#pragma unroll
            for (int j = 0; j < 4; ++j) {
                const int col = colb + j*16;
#pragma unroll
                for (int r = 0; r < 4; ++r)
                    O0[(size_t)(rowb + i*16 + r) * H + col] = (__bf16)acc[i][j][r];
            }
    } else {
        const int seg = col0 >> 10;
        if (seg == 0) {
            // delta: bias + softplus + store + per-chunk col sum (plain store).
            const int chunk = (row0 + wr) >> 6;   // b*NCH + c  (LCH==64)
#pragma unroll
            for (int j = 0; j < 4; ++j) {
                const int col = colb + j*16;
                const float bv = bias[col];
                float s = 0.f;
#pragma unroll
                for (int i = 0; i < 4; ++i)
#pragma unroll
                    for (int r = 0; r < 4; ++r) {
                        float f = acc[i][j][r] + bv;
                        f = f > 15.f ? f : log1pf(expf(f));   // softplus
                        O0[(size_t)(rowb + i*16 + r) * H + col] = (__bf16)f;
                        s += f;
                    }
                s += __shfl_down(s, 32); s += __shfl_down(s, 16);
                if (quad == 0) pD[chunk*H + col] = s;  // single writer
            }
        } else if (seg == 1) {
            // Cs tile -> LDS, column-parallel uC/Csum reduce.
            __syncthreads();   // all waves done with K-loop LDS
#pragma unroll
            for (int i = 0; i < 4; ++i)
#pragma unroll
                for (int j = 0; j < 4; ++j) {
                    const int lrow = wr + quad*4 + i*16;   // +r below
                    const int lcol = wc + j*16 + l15;
#pragma unroll
                    for (int r = 0; r < 4; ++r)
                        lds[(lrow + r)*132 + lcol] = (__bf16)acc[i][j][r];
                }
            __syncthreads();
            float* pf = reinterpret_cast<float*>(lds + 16896);
            const int col  = tid & 127;
            const int half = tid >> 7;
            const int gcol = (col0 & 1023) + col;
            const int b    = row0 >> 11;
            float su = 0.f, sc = 0.f;
#pragma unroll 8
            for (int l = 0; l < 64; ++l) {
                const int row = half*64 + l;
                float cv = (float)lds[row*132 + col];
                float xv = (float)xb[(size_t)(row0 + row)*H + gcol];
                su += xv * cv;
                sc += cv;
            }
            if (half) { pf[col] = su; pf[128 + col] = sc; }
            __syncthreads();
            if (!half) {
                su += pf[col]; sc += pf[128 + col];
                atomicAdd(pU + b*H + gcol, su);
                atomicAdd(pC + b*H + gcol, sc);
            }
        } else {
            // residual: plain store.
#pragma unroll
            for (int i = 0; i < 4; ++i)
#pragma unroll
                for (int j = 0; j < 4; ++j) {
                    const int col = colb + j*16;
#pragma unroll
                    for (int r = 0; r < 4; ++r)
                        O2[(size_t)(rowb + i*16 + r) * H + col] = (__bf16)acc[i][j][r];
                }
        }
    }
}

// ---- cast f32->bf16: x; pack W_proj segs {Cs,res}; Wd; transpose Wp1 -------
#define XB 8192   // x float4-blocks
#define PB 2048   // W_proj rows 2048..4095 pack blocks
#define DB 1024   // W_delta blocks
#define TB 256    // 64x64 transpose tiles of Wp1 (16x16 tile grid)
__global__ void cast_kernel(const float* __restrict__ x,
                            const float* __restrict__ Wp,
                            const float* __restrict__ Wd,
                            __bf16* __restrict__ xb,
                            __bf16* __restrict__ Wpb,    // [3072][1024]
                            __bf16* __restrict__ Wdb,
                            __bf16* __restrict__ Wp1T)   // [1024][1024] = Wp1^T
{
    __shared__ __bf16 tlds[64*65];
    const int t = threadIdx.x;
    const int bidx = blockIdx.x;

    if (bidx < XB + PB + DB) {
        const f32x4* src; __bf16* dst; int si, di;
        if (bidx < XB) {
            int i = bidx*256 + t;
            src = (const f32x4*)x;  si = i; dst = xb;  di = i;
        } else if (bidx < XB + PB) {
            int j = (bidx - XB)*256 + t;
            int row = j >> 8, cf = j & 255;
            src = (const f32x4*)Wp; si = (2048 + row)*256 + cf;
            dst = Wpb; di = (1024 + row)*256 + cf;
        } else {
            int j = (bidx - XB - PB)*256 + t;
            src = (const f32x4*)Wd; si = j; dst = Wdb; di = j;
        }
        f32x4 v = src[si];
        bf16x4 o = { (__bf16)v[0], (__bf16)v[1], (__bf16)v[2], (__bf16)v[3] };
        *(bf16x4*)(dst + (size_t)di*4) = o;
    } else {
        // LDS-tiled transpose of W_proj rows 0..1023 (Wp1) -> Wp1T[k][j]
        int tt = bidx - (XB + PB + DB);
        int ty = tt >> 4, tx = tt & 15;
        int rb = t >> 4, cb = t & 15;
#pragma unroll
        for (int rr = 0; rr < 4; ++rr) {
            int row = rb*4 + rr;   // j within tile
            f32x4 v = *(const f32x4*)(Wp + (size_t)(ty*64 + row)*1024 + tx*64 + cb*4);
#pragma unroll
            for (int q = 0; q < 4; ++q)
                tlds[row*65 + cb*4 + q] = (__bf16)v[q];
        }
        __syncthreads();
#pragma unroll
        for (int rr = 0; rr < 4; ++rr) {
            int kk = rb*4 + rr;    // k within tile
            bf16x4 o = { tlds[(cb*4+0)*65 + kk], tlds[(cb*4+1)*65 + kk],
                         tlds[(cb*4+2)*65 + kk], tlds[(cb*4+3)*65 + kk] };
            *(bf16x4*)(Wp1T + (size_t)(tx*64 + kk)*1024 + ty*64 + cb*4) = o;
        }
    }
}

// ------------- exclusive scan of per-chunk delta sums (in place) -------------
__global__ void scan_kernel(float* __restrict__ pD)
{
    int idx = blockIdx.x * 256 + threadIdx.x;   // 0..4095 = b*1024+h
    int b = idx >> 10, h = idx & 1023;
    float run = 0.f;
    for (int c = 0; c < NCH; ++c) {
        int p = (b*NCH + c) * H + h;
        float t = pD[p]; pD[p] = run; run += t;
    }
}

// ------------- final: y = exp(d*A1)*B1*uC + B1*cumsum(d)*Csum + res*D --------
__global__ void final_kernel(const __bf16* __restrict__ delta,
                             const __bf16* __restrict__ res,
                             const float* __restrict__ pD,
                             const float* __restrict__ uC,
                             const float* __restrict__ Csum,
                             const float* __restrict__ Av,
                             const float* __restrict__ Bv,
                             const float* __restrict__ Dv,
                             float* __restrict__ out)
{
    const int c = blockIdx.x, b = blockIdx.z;
    const int h0 = blockIdx.y * 512 + threadIdx.x * 2;
    const int pbase = (b*NCH + c)*H + h0;
    float run0 = pD[pbase], run1 = pD[pbase + 1];
    const f32x2 uc = *(const f32x2*)(uC + b*H + h0);
    const f32x2 cs = *(const f32x2*)(Csum + b*H + h0);
    const f32x2 a1 = *(const f32x2*)(Av + h0);
    const f32x2 b1 = *(const f32x2*)(Bv + h0);
    const float dd = Dv[0];
    size_t base = ((size_t)(b*LSEQ + c*LCH)) * H + h0;
    for (int l = 0; l < LCH; ++l) {
        size_t idx = base + (size_t)l * H;
        bf16x2 dv2 = *(const bf16x2*)(delta + idx);
        bf16x2 rs2 = *(const bf16x2*)(res + idx);
        float d0 = (float)dv2[0], d1v = (float)dv2[1];
        run0 += d0; run1 += d1v;
        f32x2 o;
        o[0] = expf(d0*a1[0])*b1[0]*uc[0] + run0*b1[0]*cs[0] + (float)rs2[0]*dd;
        o[1] = expf(d1v*a1[1])*b1[1]*uc[1] + run1*b1[1]*cs[1] + (float)rs2[1]*dd;
        *(f32x2*)(out + idx) = o;
    }
}

extern "C" void kernel_launch(void* const* d_in, const int* in_sizes, int n_in,
                              void* d_out, int out_size, void* d_ws, size_t ws_size,
                              hipStream_t stream)
{
    (void)in_sizes; (void)n_in; (void)out_size; (void)ws_size;
    const float* x  = (const float*)d_in[0];
    const float* Wp = (const float*)d_in[1];
    const float* Av = (const float*)d_in[2];   // (1,1,H)
    const float* Bv = (const float*)d_in[3];   // (1,H,1)
    const float* Dv = (const float*)d_in[4];   // (1,)
    const float* Wd = (const float*)d_in[5];
    const float* bd = (const float*)d_in[6];
    float* out = (float*)d_out;

    char* ws = (char*)d_ws;
    size_t o = 0;
    auto alloc = [&](size_t bytes) {
        void* p = ws + o; o += (bytes + 255) & ~(size_t)255; return p;
    };
    __bf16* xb   = (__bf16*)alloc((size_t)M_TOT * H * 2);   // 16 MB
    __bf16* Wpb  = (__bf16*)alloc((size_t)3072 * H * 2);    // rows0-1023=Wfuse, 1024-3071 packed
    __bf16* Wdb  = (__bf16*)alloc((size_t)H * H * 2);       // 2 MB
    __bf16* Wp1T = (__bf16*)alloc((size_t)H * H * 2);       // 2 MB, Wp1 transposed
    __bf16* resb = (__bf16*)alloc((size_t)M_TOT * H * 2);   // residual
    __bf16* db   = (__bf16*)alloc((size_t)M_TOT * H * 2);   // softplus(delta)
    float*  pU   = (float*)alloc((size_t)BSZ * H * 4);      // contiguous with pC
    float*  pC   = (float*)alloc((size_t)BSZ * H * 4);
    float*  pD   = (float*)alloc((size_t)BSZ * NCH * H * 4);

    hipMemsetAsync(pU, 0, (size_t)2 * BSZ * H * 4 + 256, stream);  // pU|pC only

    cast_kernel<<<XB + PB + DB + TB, 256, 0, stream>>>(
        x, Wp, Wd, xb, Wpb, Wdb, Wp1T);
    // Wfuse = Wd @ Wp1  -> Wpb rows 0..1023
    gemm_bt<32, 0><<<dim3(8, 8), 256, 0, stream>>>(
        Wdb, Wp1T, Wpb, nullptr, nullptr, nullptr, nullptr, nullptr, nullptr);
    // One big GEMM: [8192,1024] @ [3072,1024]^T
    //   seg0 -> db (+pD), seg1 -> uC/Csum atomics, seg2 -> resb
    gemm_bt<32, 2><<<dim3(24, 64), 256, 0, stream>>>(
        xb, Wpb, db, resb, xb, bd, pD, pU, pC);
    scan_kernel<<<16, 256, 0, stream>>>(pD);
    final_kernel<<<dim3(NCH, 2, BSZ), 256, 0, stream>>>(db, resb, pD, pU, pC,
                                                        Av, Bv, Dv, out);
}

// Round 5
// 203.761 us; speedup vs baseline: 1.3233x; 1.1706x over previous
//
#include <hip/hip_runtime.h>
#include <hip/hip_bf16.h>
#include <cstdint>

#define H 1024
#define BSZ 4
#define LSEQ 2048
#define M_TOT (BSZ*LSEQ)   // 8192
#define NCH 32             // L-chunks for the delta scan
#define LCH (LSEQ/NCH)     // 64

typedef __attribute__((ext_vector_type(4))) float  f32x4;
typedef __attribute__((ext_vector_type(2))) float  f32x2;
typedef __attribute__((ext_vector_type(8))) __bf16 bf16x8;
typedef __attribute__((ext_vector_type(4))) __bf16 bf16x4;
typedef __attribute__((ext_vector_type(2))) __bf16 bf16x2;

typedef __attribute__((address_space(1))) unsigned int as1_u32;
typedef __attribute__((address_space(3))) unsigned int as3_u32;

__device__ __forceinline__ void gld_lds16(const void* g, const void* l) {
    as1_u32* gp = reinterpret_cast<as1_u32*>((uintptr_t)g);
    as3_u32* lp = reinterpret_cast<as3_u32*>((uint32_t)(uintptr_t)l);
    __builtin_amdgcn_global_load_lds(gp, lp, 16, 0, 0);
}

// fast softplus: stable, native exp/log (v_exp_f32/v_log_f32), ~8 instrs
__device__ __forceinline__ float softplus_fast(float f) {
    return fmaxf(f, 0.f) + __logf(1.f + __expf(-fabsf(f)));
}

// ---------------- GEMM: C[M,N] = A[M,K] @ B[N,K]^T, bf16 in ----------------
// 128x128 tile, 4 waves x (4x4) mfma_f32_16x16x32_bf16, double-buffered LDS,
// one barrier per K-tile, XOR-swizzled 16B granules.
// MODE 0: plain store to O0 (Wfuse = Wd @ Wp1).
// MODE 2 (the big GEMM, N=3072):
//   seg0 (delta = x@Wfuse^T+b): fast softplus, store db, per-64-row-chunk
//     col-sum -> pD plain store (single writer per (chunk,col)).
//   seg1 (Cs): never stored. Tile -> LDS [128][136] bf16, each thread
//     reduces 8 rows x 8 cols (bf16x8 LDS + coalesced 16B xb loads),
//     cross-group LDS reduce -> PLAIN-STORE partials pUp/pCp[rb][1024].
//   seg2 (residual): store O2.
template<int KT, int MODE>
__global__ __launch_bounds__(256, 3) void gemm_bt(
    const __bf16* __restrict__ A,
    const __bf16* __restrict__ B,
    __bf16* __restrict__ O0,
    __bf16* __restrict__ O2,
    const __bf16* __restrict__ xb,
    const float* __restrict__ bias,
    float* __restrict__ pD,
    float* __restrict__ pUp,    // [64][1024] partial sum(x*Cs) per 128-row blk
    float* __restrict__ pCp)    // [64][1024] partial sum(Cs)
{
    constexpr int K = KT * 32;
    // K-loop: [0,16384) = 2 x (A:4096 | B:4096) bf16.
    // seg1 epilogue reuses all of it: 128x136 bf16 tile (=17408 elems).
    __shared__ __align__(16) __bf16 lds[17408];

    const int tid  = threadIdx.x;
    const int lane = tid & 63;
    const int wid  = tid >> 6;
    const int wr   = (wid >> 1) * 64;
    const int wc   = (wid & 1) * 64;
    const int l15  = lane & 15;
    const int quad = lane >> 4;

    const int row0 = blockIdx.y * 128;
    const int col0 = blockIdx.x * 128;

    const int srow = lane >> 2;
    const int soct = (lane & 3) ^ ((lane >> 3) & 3);   // XOR swizzle at store
    const __bf16* ag0 = A + (size_t)(row0 + (wid    )*16 + srow) * K + soct*8;
    const __bf16* ag1 = A + (size_t)(row0 + (wid + 4)*16 + srow) * K + soct*8;
    const __bf16* bg0 = B + (size_t)(col0 + (wid    )*16 + srow) * K + soct*8;
    const __bf16* bg1 = B + (size_t)(col0 + (wid + 4)*16 + srow) * K + soct*8;
    const int lA0 = (wid    )*512;
    const int lA1 = (wid + 4)*512;
    const int lB0 = 4096 + (wid    )*512;
    const int lB1 = 4096 + (wid + 4)*512;

    const int sw = (l15 >> 1) & 3;
    int aoff[4], boff[4];
#pragma unroll
    for (int i = 0; i < 4; ++i) {
        aoff[i] =        ((wr + i*16 + l15) * 4 + (quad ^ sw)) * 8;
        boff[i] = 4096 + ((wc + i*16 + l15) * 4 + (quad ^ sw)) * 8;
    }

    f32x4 acc[4][4] = {};

    auto stage = [&](int buf) {
        __bf16* base = lds + buf * 8192;
        gld_lds16(ag0, base + lA0);
        gld_lds16(ag1, base + lA1);
        gld_lds16(bg0, base + lB0);
        gld_lds16(bg1, base + lB1);
        ag0 += 32; ag1 += 32; bg0 += 32; bg1 += 32;
    };
    auto compute = [&](int buf) {
        const __bf16* base = lds + buf * 8192;
        bf16x8 af[4], bf[4];
#pragma unroll
        for (int i = 0; i < 4; ++i) af[i] = *(const bf16x8*)(base + aoff[i]);
#pragma unroll
        for (int j = 0; j < 4; ++j) bf[j] = *(const bf16x8*)(base + boff[j]);
#pragma unroll
        for (int i = 0; i < 4; ++i)
#pragma unroll
            for (int j = 0; j < 4; ++j)
                acc[i][j] = __builtin_amdgcn_mfma_f32_16x16x32_bf16(
                    af[i], bf[j], acc[i][j], 0, 0, 0);
    };

    stage(0);
#pragma unroll 2
    for (int kt = 0; kt < KT; ++kt) {
        __syncthreads();
        if (kt + 1 < KT) stage((kt + 1) & 1);
        compute(kt & 1);
    }

    // epilogue. C/D layout: col=lane&15, row=quad*4+reg (verified m89/m91).
    const int colb = (col0 & 1023) + wc + l15;
    const int rowb = row0 + wr + quad*4;

    if (MODE == 0) {
#pragma unroll
        for (int i = 0; i < 4; ++i)
#pragma unroll
            for (int j = 0; j < 4; ++j) {
                const int col = colb + j*16;
#pragma unroll
                for (int r = 0; r < 4; ++r)
                    O0[(size_t)(rowb + i*16 + r) * H + col] = (__bf16)acc[i][j][r];
            }
    } else {
        const int seg = col0 >> 10;
        if (seg == 0) {
            // delta: bias + fast softplus + store + per-chunk col sum.
            const int chunk = (row0 + wr) >> 6;   // b*NCH + c  (LCH==64)
#pragma unroll
            for (int j = 0; j < 4; ++j) {
                const int col = colb + j*16;
                const float bv = bias[col];
                float s = 0.f;
#pragma unroll
                for (int i = 0; i < 4; ++i)
#pragma unroll
                    for (int r = 0; r < 4; ++r) {
                        float f = softplus_fast(acc[i][j][r] + bv);
                        O0[(size_t)(rowb + i*16 + r) * H + col] = (__bf16)f;
                        s += f;
                    }
                s += __shfl_down(s, 32); s += __shfl_down(s, 16);
                if (quad == 0) pD[chunk*H + col] = s;  // single writer
            }
        } else if (seg == 1) {
            // Cs tile -> LDS [128][136] bf16 (16B-aligned rows).
            __syncthreads();   // all waves done with K-loop LDS reads
#pragma unroll
            for (int i = 0; i < 4; ++i)
#pragma unroll
                for (int j = 0; j < 4; ++j) {
                    const int lrow0 = wr + quad*4 + i*16;
                    const int lcol  = wc + j*16 + l15;
#pragma unroll
                    for (int r = 0; r < 4; ++r)
                        lds[(lrow0 + r)*136 + lcol] = (__bf16)acc[i][j][r];
                }
            __syncthreads();
            // thread (g,oct): rows g*8..g*8+7, cols oct*8..oct*8+7
            const int g   = tid >> 4;
            const int oct = tid & 15;
            const int gc0 = (col0 & 1023) + oct*8;
            float su[8] = {}, sc[8] = {};
#pragma unroll
            for (int rr = 0; rr < 8; ++rr) {
                const int lrow = g*8 + rr;
                bf16x8 cv = *(const bf16x8*)(lds + lrow*136 + oct*8);
                bf16x8 xv = *(const bf16x8*)(xb + (size_t)(row0 + lrow)*H + gc0);
#pragma unroll
                for (int q = 0; q < 8; ++q) {
                    float c = (float)cv[q];
                    su[q] += (float)xv[q] * c;
                    sc[q] += c;
                }
            }
            // cross-rowgroup reduce via LDS f32 [16][128] x2 (reuse lds)
            float* pf = reinterpret_cast<float*>(lds);
            __syncthreads();   // done reading Cs tile
#pragma unroll
            for (int q = 0; q < 8; ++q) {
                pf[g*128 + oct*8 + q]        = su[q];
                pf[2048 + g*128 + oct*8 + q] = sc[q];
            }
            __syncthreads();
            const int col = tid & 127;
            const int rb  = row0 >> 7;        // global 128-row block 0..63
            float s = 0.f;
            if (tid < 128) {
#pragma unroll
                for (int g2 = 0; g2 < 16; ++g2) s += pf[g2*128 + col];
                pUp[rb*H + (col0 & 1023) + col] = s;
            } else {
#pragma unroll
                for (int g2 = 0; g2 < 16; ++g2) s += pf[2048 + g2*128 + col];
                pCp[rb*H + (col0 & 1023) + col] = s;
            }
        } else {
            // residual: plain store.
#pragma unroll
            for (int i = 0; i < 4; ++i)
#pragma unroll
                for (int j = 0; j < 4; ++j) {
                    const int col = colb + j*16;
#pragma unroll
                    for (int r = 0; r < 4; ++r)
                        O2[(size_t)(rowb + i*16 + r) * H + col] = (__bf16)acc[i][j][r];
                }
        }
    }
}

// ---- cast f32->bf16: x; pack W_proj segs {Cs,res}; Wd; transpose Wp1 -------
#define XB 8192   // x float4-blocks
#define PB 2048   // W_proj rows 2048..4095 pack blocks
#define DB 1024   // W_delta blocks
#define TB 256    // 64x64 transpose tiles of Wp1 (16x16 tile grid)
__global__ void cast_kernel(const float* __restrict__ x,
                            const float* __restrict__ Wp,
                            const float* __restrict__ Wd,
                            __bf16* __restrict__ xb,
                            __bf16* __restrict__ Wpb,    // [3072][1024]
                            __bf16* __restrict__ Wdb,
                            __bf16* __restrict__ Wp1T)   // [1024][1024] = Wp1^T
{
    __shared__ __bf16 tlds[64*65];
    const int t = threadIdx.x;
    const int bidx = blockIdx.x;

    if (bidx < XB + PB + DB) {
        const f32x4* src; __bf16* dst; int si, di;
        if (bidx < XB) {
            int i = bidx*256 + t;
            src = (const f32x4*)x;  si = i; dst = xb;  di = i;
        } else if (bidx < XB + PB) {
            int j = (bidx - XB)*256 + t;
            int row = j >> 8, cf = j & 255;
            src = (const f32x4*)Wp; si = (2048 + row)*256 + cf;
            dst = Wpb; di = (1024 + row)*256 + cf;
        } else {
            int j = (bidx - XB - PB)*256 + t;
            src = (const f32x4*)Wd; si = j; dst = Wdb; di = j;
        }
        f32x4 v = src[si];
        bf16x4 o = { (__bf16)v[0], (__bf16)v[1], (__bf16)v[2], (__bf16)v[3] };
        *(bf16x4*)(dst + (size_t)di*4) = o;
    } else {
        // LDS-tiled transpose of W_proj rows 0..1023 (Wp1) -> Wp1T[k][j]
        int tt = bidx - (XB + PB + DB);
        int ty = tt >> 4, tx = tt & 15;
        int rb = t >> 4, cb = t & 15;
#pragma unroll
        for (int rr = 0; rr < 4; ++rr) {
            int row = rb*4 + rr;
            f32x4 v = *(const f32x4*)(Wp + (size_t)(ty*64 + row)*1024 + tx*64 + cb*4);
#pragma unroll
            for (int q = 0; q < 4; ++q)
                tlds[row*65 + cb*4 + q] = (__bf16)v[q];
        }
        __syncthreads();
#pragma unroll
        for (int rr = 0; rr < 4; ++rr) {
            int kk = rb*4 + rr;
            bf16x4 o = { tlds[(cb*4+0)*65 + kk], tlds[(cb*4+1)*65 + kk],
                         tlds[(cb*4+2)*65 + kk], tlds[(cb*4+3)*65 + kk] };
            *(bf16x4*)(Wp1T + (size_t)(tx*64 + kk)*1024 + ty*64 + cb*4) = o;
        }
    }
}

// ---- final: inline chunk-prefix + partial-sum gather + elementwise combine --
// y = exp(d*A1)*B1*uC + B1*cumsum(d)*Csum + res*D
__global__ void final_kernel(const __bf16* __restrict__ delta,
                             const __bf16* __restrict__ res,
                             const float* __restrict__ pD,   // [128][1024] chunk sums
                             const float* __restrict__ pUp,  // [64][1024]
                             const float* __restrict__ pCp,  // [64][1024]
                             const float* __restrict__ Av,
                             const float* __restrict__ Bv,
                             const float* __restrict__ Dv,
                             float* __restrict__ out)
{
    const int c = blockIdx.x, b = blockIdx.z;
    const int h0 = blockIdx.y * 512 + threadIdx.x * 2;
    // exclusive prefix of chunk sums for this (b, c)
    float run0 = 0.f, run1 = 0.f;
    for (int cp = 0; cp < c; ++cp) {
        f32x2 v = *(const f32x2*)(pD + (b*NCH + cp)*H + h0);
        run0 += v[0]; run1 += v[1];
    }
    // uC / Csum from 16 row-block partials
    float uc0 = 0.f, uc1 = 0.f, cs0 = 0.f, cs1 = 0.f;
#pragma unroll
    for (int i = 0; i < 16; ++i) {
        f32x2 u = *(const f32x2*)(pUp + (b*16 + i)*H + h0);
        f32x2 s = *(const f32x2*)(pCp + (b*16 + i)*H + h0);
        uc0 += u[0]; uc1 += u[1]; cs0 += s[0]; cs1 += s[1];
    }
    const f32x2 a1 = *(const f32x2*)(Av + h0);
    const f32x2 b1 = *(const f32x2*)(Bv + h0);
    const float dd = Dv[0];
    size_t base = ((size_t)(b*LSEQ + c*LCH)) * H + h0;
    for (int l = 0; l < LCH; ++l) {
        size_t idx = base + (size_t)l * H;
        bf16x2 dv2 = *(const bf16x2*)(delta + idx);
        bf16x2 rs2 = *(const bf16x2*)(res + idx);
        float d0 = (float)dv2[0], d1v = (float)dv2[1];
        run0 += d0; run1 += d1v;
        f32x2 o;
        o[0] = __expf(d0*a1[0])*b1[0]*uc0 + run0*b1[0]*cs0 + (float)rs2[0]*dd;
        o[1] = __expf(d1v*a1[1])*b1[1]*uc1 + run1*b1[1]*cs1 + (float)rs2[1]*dd;
        *(f32x2*)(out + idx) = o;
    }
}

extern "C" void kernel_launch(void* const* d_in, const int* in_sizes, int n_in,
                              void* d_out, int out_size, void* d_ws, size_t ws_size,
                              hipStream_t stream)
{
    (void)in_sizes; (void)n_in; (void)out_size; (void)ws_size;
    const float* x  = (const float*)d_in[0];
    const float* Wp = (const float*)d_in[1];
    const float* Av = (const float*)d_in[2];   // (1,1,H)
    const float* Bv = (const float*)d_in[3];   // (1,H,1)
    const float* Dv = (const float*)d_in[4];   // (1,)
    const float* Wd = (const float*)d_in[5];
    const float* bd = (const float*)d_in[6];
    float* out = (float*)d_out;

    char* ws = (char*)d_ws;
    size_t o = 0;
    auto alloc = [&](size_t bytes) {
        void* p = ws + o; o += (bytes + 255) & ~(size_t)255; return p;
    };
    __bf16* xb   = (__bf16*)alloc((size_t)M_TOT * H * 2);   // 16 MB
    __bf16* Wpb  = (__bf16*)alloc((size_t)3072 * H * 2);    // rows0-1023=Wfuse
    __bf16* Wdb  = (__bf16*)alloc((size_t)H * H * 2);
    __bf16* Wp1T = (__bf16*)alloc((size_t)H * H * 2);
    __bf16* resb = (__bf16*)alloc((size_t)M_TOT * H * 2);   // residual
    __bf16* db   = (__bf16*)alloc((size_t)M_TOT * H * 2);   // softplus(delta)
    float*  pD   = (float*)alloc((size_t)BSZ * NCH * H * 4);   // chunk sums
    float*  pUp  = (float*)alloc((size_t)64 * H * 4);          // row-blk partials
    float*  pCp  = (float*)alloc((size_t)64 * H * 4);

    cast_kernel<<<XB + PB + DB + TB, 256, 0, stream>>>(
        x, Wp, Wd, xb, Wpb, Wdb, Wp1T);
    // Wfuse = Wd @ Wp1  -> Wpb rows 0..1023
    gemm_bt<32, 0><<<dim3(8, 8), 256, 0, stream>>>(
        Wdb, Wp1T, Wpb, nullptr, nullptr, nullptr, nullptr, nullptr, nullptr);
    // Big GEMM: [8192,1024] @ [3072,1024]^T
    //   seg0 -> db (+pD), seg1 -> pUp/pCp partials, seg2 -> resb
    gemm_bt<32, 2><<<dim3(24, 64), 256, 0, stream>>>(
        xb, Wpb, db, resb, xb, bd, pD, pUp, pCp);
    final_kernel<<<dim3(NCH, 2, BSZ), 256, 0, stream>>>(db, resb, pD, pUp, pCp,
                                                        Av, Bv, Dv, out);
}